// Round 1
// baseline (1304.415 us; speedup 1.0000x reference)
//
#include <hip/hip_runtime.h>
#include <math.h>

#define D 128
#define NCLS 40

// ---------------- CSR build ----------------

__global__ void count_deg_k(const int* __restrict__ dst, int* __restrict__ deg, int E){
  int e = blockIdx.x * blockDim.x + threadIdx.x;
  if (e < E) atomicAdd(&deg[dst[e]], 1);
}

// generic exclusive block scan (Hillis-Steele in LDS); bsum gets block totals
__global__ void scan_excl_k(const int* __restrict__ in, int* __restrict__ out,
                            int* __restrict__ bsum, int n){
  __shared__ int sm[1024];
  int tid = threadIdx.x;
  int i = blockIdx.x * blockDim.x + tid;
  int v = (i < n) ? in[i] : 0;
  sm[tid] = v; __syncthreads();
  int acc = v;
  for (int off = 1; off < (int)blockDim.x; off <<= 1){
    int t = (tid >= off) ? sm[tid - off] : 0;
    __syncthreads();
    acc += t; sm[tid] = acc;
    __syncthreads();
  }
  if (i < n) out[i] = acc - v;          // exclusive
  if (bsum && tid == (int)blockDim.x - 1) bsum[blockIdx.x] = acc;
}

__global__ void finalize_k(int* __restrict__ csr_off, const int* __restrict__ bsum_s,
                           const int* __restrict__ deg, float* __restrict__ deg_inv,
                           int n, int E){
  int i = blockIdx.x * blockDim.x + threadIdx.x;
  if (i < n){
    csr_off[i] += bsum_s[i >> 10];      // scan1 blocks were 1024 wide
    deg_inv[i] = 1.0f / fmaxf((float)deg[i], 1.0f);
  }
  if (i == 0) csr_off[n] = E;
}

__global__ void fill_csr_k(const int* __restrict__ src, const int* __restrict__ dst,
                           const int* __restrict__ coff, int* __restrict__ pos,
                           int* __restrict__ csr_src, int E){
  int e = blockIdx.x * blockDim.x + threadIdx.x;
  if (e < E){
    int d = dst[e];
    int p = atomicAdd(&pos[d], 1);
    csr_src[coff[d] + p] = src[e];
  }
}

// ---------------- mean aggregation (gather via CSR) ----------------
// one block (128 threads) per node; thread = feature channel
__global__ void aggregate_k(const float* __restrict__ feat, const int* __restrict__ coff,
                            const int* __restrict__ csr_src, const float* __restrict__ deg_inv,
                            float* __restrict__ agg, int n){
  int node = blockIdx.x;
  int tid = threadIdx.x;
  int lo = coff[node], hi = coff[node + 1];
  float acc = 0.f;
  for (int e = lo; e < hi; ++e){
    int s = csr_src[e];
    acc += feat[(size_t)s * D + tid];
  }
  agg[(size_t)node * D + tid] = acc * deg_inv[node];
}

// ---------------- dense: out = relu(A1@B1 + bias + A2@B2), all [*,128] ----------------
// K=256 concatenated GEMM. 128x128 tile, BK=8, 256 threads, 8x8 micro-tile.
__global__ __launch_bounds__(256) void gemm2_relu_k(
    const float* __restrict__ A1, const float* __restrict__ A2,
    const float* __restrict__ B1, const float* __restrict__ B2,
    const float* __restrict__ bias, float* __restrict__ out, int n)
{
  __shared__ float As[8][128];
  __shared__ float Bs[8][128];
  const int tid = threadIdx.x;
  const int row0 = blockIdx.x * 128;
  const int tx = tid & 15, ty = tid >> 4;
  const int lam = tid >> 1, lak = (tid & 1) * 4;     // A: row-in-tile, k offset
  const int lbk = tid >> 5, lbn = (tid & 31) * 4;    // B: k row, col offset
  float acc[8][8];
  #pragma unroll
  for (int i = 0; i < 8; i++)
    #pragma unroll
    for (int j = 0; j < 8; j++) acc[i][j] = 0.f;

  const int arow = row0 + lam;
  for (int kt = 0; kt < 32; ++kt){
    const int kg = kt * 8;
    const float* Ap = (kg < 128) ? A1 : A2;
    const float* Bp = (kg < 128) ? B1 : B2;
    const int kl = kg & 127;
    float4 av = make_float4(0.f, 0.f, 0.f, 0.f);
    if (arow < n) av = *(const float4*)(Ap + (size_t)arow * 128 + kl + lak);
    float4 bv = *(const float4*)(Bp + (size_t)(kl + lbk) * 128 + lbn);
    As[lak + 0][lam] = av.x; As[lak + 1][lam] = av.y;
    As[lak + 2][lam] = av.z; As[lak + 3][lam] = av.w;
    *(float4*)&Bs[lbk][lbn] = bv;
    __syncthreads();
    #pragma unroll
    for (int kk = 0; kk < 8; kk++){
      float a[8], b[8];
      *(float4*)&a[0] = *(const float4*)&As[kk][ty * 8];
      *(float4*)&a[4] = *(const float4*)&As[kk][ty * 8 + 4];
      *(float4*)&b[0] = *(const float4*)&Bs[kk][tx * 8];
      *(float4*)&b[4] = *(const float4*)&Bs[kk][tx * 8 + 4];
      #pragma unroll
      for (int i = 0; i < 8; i++)
        #pragma unroll
        for (int j = 0; j < 8; j++) acc[i][j] = fmaf(a[i], b[j], acc[i][j]);
    }
    __syncthreads();
  }
  float bcol[8];
  #pragma unroll
  for (int j = 0; j < 8; j++) bcol[j] = bias[tx * 8 + j];
  #pragma unroll
  for (int i = 0; i < 8; i++){
    int r = row0 + ty * 8 + i;
    if (r < n){
      float4 v0, v1;
      v0.x = fmaxf(acc[i][0] + bcol[0], 0.f);
      v0.y = fmaxf(acc[i][1] + bcol[1], 0.f);
      v0.z = fmaxf(acc[i][2] + bcol[2], 0.f);
      v0.w = fmaxf(acc[i][3] + bcol[3], 0.f);
      v1.x = fmaxf(acc[i][4] + bcol[4], 0.f);
      v1.y = fmaxf(acc[i][5] + bcol[5], 0.f);
      v1.z = fmaxf(acc[i][6] + bcol[6], 0.f);
      v1.w = fmaxf(acc[i][7] + bcol[7], 0.f);
      *(float4*)(out + (size_t)r * 128 + tx * 8) = v0;
      *(float4*)(out + (size_t)r * 128 + tx * 8 + 4) = v1;
    }
  }
}

// ---------------- layer 3 + log_softmax: one wave per node, lane = class ----------------
__global__ __launch_bounds__(256) void layer3_k(
    const float* __restrict__ agg, const float* __restrict__ h,
    const float* __restrict__ Wl, const float* __restrict__ bias,
    const float* __restrict__ Wr, float* __restrict__ out, int n)
{
  int wave = threadIdx.x >> 6;
  int lane = threadIdx.x & 63;
  int node = blockIdx.x * 4 + wave;
  if (node >= n) return;
  const float* ar = agg + (size_t)node * 128;
  const float* hr = h + (size_t)node * 128;
  float v;
  if (lane < NCLS){
    float s = bias[lane];
    #pragma unroll 4
    for (int k = 0; k < 128; k++){
      s = fmaf(ar[k], Wl[k * NCLS + lane], s);
      s = fmaf(hr[k], Wr[k * NCLS + lane], s);
    }
    v = s;
  } else {
    v = -INFINITY;
  }
  float m = v;
  #pragma unroll
  for (int off = 32; off > 0; off >>= 1) m = fmaxf(m, __shfl_xor(m, off, 64));
  float ex = (lane < NCLS) ? __expf(v - m) : 0.f;
  float ssum = ex;
  #pragma unroll
  for (int off = 32; off > 0; off >>= 1) ssum += __shfl_xor(ssum, off, 64);
  if (lane < NCLS) out[(size_t)node * NCLS + lane] = v - m - logf(ssum);
}

// ---------------- launch ----------------

extern "C" void kernel_launch(void* const* d_in, const int* in_sizes, int n_in,
                              void* d_out, int out_size, void* d_ws, size_t ws_size,
                              hipStream_t stream) {
  const float* x   = (const float*)d_in[0];
  const int*   ei  = (const int*)d_in[1];
  const float* W1l = (const float*)d_in[2];
  const float* b1  = (const float*)d_in[3];
  const float* W1r = (const float*)d_in[4];
  const float* W2l = (const float*)d_in[5];
  const float* b2  = (const float*)d_in[6];
  const float* W2r = (const float*)d_in[7];
  const float* W3l = (const float*)d_in[8];
  const float* b3  = (const float*)d_in[9];
  const float* W3r = (const float*)d_in[10];

  const int N = in_sizes[0] / D;       // 100000
  const int E = in_sizes[1] / 2;       // 1600000
  const int* src = ei;
  const int* dst = ei + E;

  char* ws = (char*)d_ws;
  auto alloc = [&](size_t bytes) -> void* {
    void* p = (void*)ws;
    ws += (bytes + 255) & ~(size_t)255;
    return p;
  };
  int*   deg_i    = (int*)  alloc((size_t)N * 4);
  int*   csr_off  = (int*)  alloc((size_t)(N + 1) * 4);
  int*   fill_pos = (int*)  alloc((size_t)N * 4);
  int*   bsum     = (int*)  alloc(1024);
  int*   bsum_s   = (int*)  alloc(1024);
  float* deg_inv  = (float*)alloc((size_t)N * 4);
  int*   csr_src  = (int*)  alloc((size_t)E * 4);
  float* agg      = (float*)alloc((size_t)N * D * 4);
  float* hbuf     = (float*)alloc((size_t)N * D * 4);

  hipMemsetAsync(deg_i, 0, (size_t)N * 4, stream);
  hipMemsetAsync(fill_pos, 0, (size_t)N * 4, stream);

  // CSR build
  count_deg_k<<<(E + 255) / 256, 256, 0, stream>>>(dst, deg_i, E);
  const int NB = (N + 1023) / 1024;
  scan_excl_k<<<NB, 1024, 0, stream>>>(deg_i, csr_off, bsum, N);
  scan_excl_k<<<1, 128, 0, stream>>>(bsum, bsum_s, nullptr, NB);
  finalize_k<<<(N + 255) / 256, 256, 0, stream>>>(csr_off, bsum_s, deg_i, deg_inv, N, E);
  fill_csr_k<<<(E + 255) / 256, 256, 0, stream>>>(src, dst, csr_off, fill_pos, csr_src, E);

  const int gblocks = (N + 127) / 128;
  // layer 1
  aggregate_k<<<N, 128, 0, stream>>>(x, csr_off, csr_src, deg_inv, agg, N);
  gemm2_relu_k<<<gblocks, 256, 0, stream>>>(agg, x, W1l, W1r, b1, hbuf, N);
  // layer 2 (in-place h: each block reads only its own row tile before writing it)
  aggregate_k<<<N, 128, 0, stream>>>(hbuf, csr_off, csr_src, deg_inv, agg, N);
  gemm2_relu_k<<<gblocks, 256, 0, stream>>>(agg, hbuf, W2l, W2r, b2, hbuf, N);
  // layer 3 + log_softmax
  aggregate_k<<<N, 128, 0, stream>>>(hbuf, csr_off, csr_src, deg_inv, agg, N);
  layer3_k<<<(N + 3) / 4, 256, 0, stream>>>(agg, hbuf, W3l, b3, W3r, (float*)d_out, N);
}

// Round 2
// 867.057 us; speedup vs baseline: 1.5044x; 1.5044x over previous
//
#include <hip/hip_runtime.h>
#include <math.h>

#define D 128
#define NCLS 40

// ---------------- CSR build ----------------

__global__ void count_deg_k(const int* __restrict__ dst, int* __restrict__ deg, int E){
  int e = blockIdx.x * blockDim.x + threadIdx.x;
  if (e < E) atomicAdd(&deg[dst[e]], 1);
}

__global__ void scan_excl_k(const int* __restrict__ in, int* __restrict__ out,
                            int* __restrict__ bsum, int n){
  __shared__ int sm[1024];
  int tid = threadIdx.x;
  int i = blockIdx.x * blockDim.x + tid;
  int v = (i < n) ? in[i] : 0;
  sm[tid] = v; __syncthreads();
  int acc = v;
  for (int off = 1; off < (int)blockDim.x; off <<= 1){
    int t = (tid >= off) ? sm[tid - off] : 0;
    __syncthreads();
    acc += t; sm[tid] = acc;
    __syncthreads();
  }
  if (i < n) out[i] = acc - v;          // exclusive
  if (bsum && tid == (int)blockDim.x - 1) bsum[blockIdx.x] = acc;
}

__global__ void finalize_k(int* __restrict__ csr_off, const int* __restrict__ bsum_s,
                           const int* __restrict__ deg, float* __restrict__ deg_inv,
                           int n, int E){
  int i = blockIdx.x * blockDim.x + threadIdx.x;
  if (i < n){
    csr_off[i] += bsum_s[i >> 10];
    deg_inv[i] = 1.0f / fmaxf((float)deg[i], 1.0f);
  }
  if (i == 0) csr_off[n] = E;
}

__global__ void fill_csr_k(const int* __restrict__ src, const int* __restrict__ dst,
                           const int* __restrict__ coff, int* __restrict__ pos,
                           int* __restrict__ csr_src, int E){
  int e = blockIdx.x * blockDim.x + threadIdx.x;
  if (e < E){
    int d = dst[e];
    int p = atomicAdd(&pos[d], 1);
    csr_src[coff[d] + p] = src[e];
  }
}

// ---------------- mean aggregation (gather via CSR) ----------------
// 32 lanes per node (float4 each = full 512B row per gather); 8 nodes per 256-thread block
__global__ __launch_bounds__(256) void aggregate_k(
    const float* __restrict__ feat, const int* __restrict__ coff,
    const int* __restrict__ csr_src, const float* __restrict__ deg_inv,
    float* __restrict__ agg, int n)
{
  const int g = threadIdx.x >> 5;
  const int lane = threadIdx.x & 31;
  const int node = blockIdx.x * 8 + g;
  if (node >= n) return;
  const int lo = coff[node], hi = coff[node + 1];
  const float4* __restrict__ f4 = (const float4*)feat;
  float4 acc = make_float4(0.f, 0.f, 0.f, 0.f);
  int e = lo;
  for (; e + 1 < hi; e += 2){
    int s0 = csr_src[e], s1 = csr_src[e + 1];
    float4 v0 = f4[(size_t)s0 * 32 + lane];
    float4 v1 = f4[(size_t)s1 * 32 + lane];
    acc.x += v0.x + v1.x; acc.y += v0.y + v1.y;
    acc.z += v0.z + v1.z; acc.w += v0.w + v1.w;
  }
  if (e < hi){
    int s0 = csr_src[e];
    float4 v0 = f4[(size_t)s0 * 32 + lane];
    acc.x += v0.x; acc.y += v0.y; acc.z += v0.z; acc.w += v0.w;
  }
  const float di = deg_inv[node];
  acc.x *= di; acc.y *= di; acc.z *= di; acc.w *= di;
  ((float4*)agg)[(size_t)node * 32 + lane] = acc;
}

// ---------------- dense: out = relu(A1@B1 + bias + A2@B2), all [*,128] ----------------
__global__ __launch_bounds__(256) void gemm2_relu_k(
    const float* __restrict__ A1, const float* __restrict__ A2,
    const float* __restrict__ B1, const float* __restrict__ B2,
    const float* __restrict__ bias, float* __restrict__ out, int n)
{
  __shared__ float As[8][128];
  __shared__ float Bs[8][128];
  const int tid = threadIdx.x;
  const int row0 = blockIdx.x * 128;
  const int tx = tid & 15, ty = tid >> 4;
  const int lam = tid >> 1, lak = (tid & 1) * 4;
  const int lbk = tid >> 5, lbn = (tid & 31) * 4;
  float acc[8][8];
  #pragma unroll
  for (int i = 0; i < 8; i++)
    #pragma unroll
    for (int j = 0; j < 8; j++) acc[i][j] = 0.f;

  const int arow = row0 + lam;
  for (int kt = 0; kt < 32; ++kt){
    const int kg = kt * 8;
    const float* Ap = (kg < 128) ? A1 : A2;
    const float* Bp = (kg < 128) ? B1 : B2;
    const int kl = kg & 127;
    float4 av = make_float4(0.f, 0.f, 0.f, 0.f);
    if (arow < n) av = *(const float4*)(Ap + (size_t)arow * 128 + kl + lak);
    float4 bv = *(const float4*)(Bp + (size_t)(kl + lbk) * 128 + lbn);
    As[lak + 0][lam] = av.x; As[lak + 1][lam] = av.y;
    As[lak + 2][lam] = av.z; As[lak + 3][lam] = av.w;
    *(float4*)&Bs[lbk][lbn] = bv;
    __syncthreads();
    #pragma unroll
    for (int kk = 0; kk < 8; kk++){
      float a[8], b[8];
      *(float4*)&a[0] = *(const float4*)&As[kk][ty * 8];
      *(float4*)&a[4] = *(const float4*)&As[kk][ty * 8 + 4];
      *(float4*)&b[0] = *(const float4*)&Bs[kk][tx * 8];
      *(float4*)&b[4] = *(const float4*)&Bs[kk][tx * 8 + 4];
      #pragma unroll
      for (int i = 0; i < 8; i++)
        #pragma unroll
        for (int j = 0; j < 8; j++) acc[i][j] = fmaf(a[i], b[j], acc[i][j]);
    }
    __syncthreads();
  }
  float bcol[8];
  #pragma unroll
  for (int j = 0; j < 8; j++) bcol[j] = bias[tx * 8 + j];
  #pragma unroll
  for (int i = 0; i < 8; i++){
    int r = row0 + ty * 8 + i;
    if (r < n){
      float4 v0, v1;
      v0.x = fmaxf(acc[i][0] + bcol[0], 0.f);
      v0.y = fmaxf(acc[i][1] + bcol[1], 0.f);
      v0.z = fmaxf(acc[i][2] + bcol[2], 0.f);
      v0.w = fmaxf(acc[i][3] + bcol[3], 0.f);
      v1.x = fmaxf(acc[i][4] + bcol[4], 0.f);
      v1.y = fmaxf(acc[i][5] + bcol[5], 0.f);
      v1.z = fmaxf(acc[i][6] + bcol[6], 0.f);
      v1.w = fmaxf(acc[i][7] + bcol[7], 0.f);
      *(float4*)(out + (size_t)r * 128 + tx * 8) = v0;
      *(float4*)(out + (size_t)r * 128 + tx * 8 + 4) = v1;
    }
  }
}

// ---------------- layer 3 + log_softmax: one THREAD per node; W3 in LDS ----------------
__global__ __launch_bounds__(128) void layer3_k(
    const float* __restrict__ agg, const float* __restrict__ h,
    const float* __restrict__ Wl, const float* __restrict__ bias,
    const float* __restrict__ Wr, float* __restrict__ out, int n)
{
  __shared__ float Wls[D * NCLS];   // 5120 floats = 20 KB
  __shared__ float Wrs[D * NCLS];   // 20 KB
  const int tid = threadIdx.x;
  // cooperative load: 5120 floats / 128 threads = 40 each = 10 float4
  for (int i = tid * 4; i < D * NCLS; i += 128 * 4){
    *(float4*)&Wls[i] = *(const float4*)&Wl[i];
    *(float4*)&Wrs[i] = *(const float4*)&Wr[i];
  }
  __syncthreads();
  const int node = blockIdx.x * 128 + tid;
  if (node >= n) return;
  const float4* __restrict__ ar = (const float4*)(agg + (size_t)node * D);
  const float4* __restrict__ hr = (const float4*)(h + (size_t)node * D);
  float acc[NCLS];
  #pragma unroll
  for (int c = 0; c < NCLS; c++) acc[c] = bias[c];
  for (int k4 = 0; k4 < D / 4; k4++){
    float4 a = ar[k4];
    float4 b = hr[k4];
    const float* av = (const float*)&a;
    const float* hv = (const float*)&b;
    #pragma unroll
    for (int j = 0; j < 4; j++){
      const float afv = av[j], hfv = hv[j];
      const float* __restrict__ wl = &Wls[(k4 * 4 + j) * NCLS];
      const float* __restrict__ wr = &Wrs[(k4 * 4 + j) * NCLS];
      #pragma unroll
      for (int c = 0; c < NCLS; c++)
        acc[c] = fmaf(afv, wl[c], fmaf(hfv, wr[c], acc[c]));
    }
  }
  // log_softmax over the 40 register values
  float m = -INFINITY;
  #pragma unroll
  for (int c = 0; c < NCLS; c++) m = fmaxf(m, acc[c]);
  float s = 0.f;
  #pragma unroll
  for (int c = 0; c < NCLS; c++) s += __expf(acc[c] - m);
  const float ls = m + logf(s);
  float* op = out + (size_t)node * NCLS;   // node*160B is 16B-aligned
  #pragma unroll
  for (int c = 0; c < NCLS; c++) acc[c] -= ls;
  #pragma unroll
  for (int c4 = 0; c4 < NCLS / 4; c4++)
    *(float4*)(op + c4 * 4) = make_float4(acc[c4*4], acc[c4*4+1], acc[c4*4+2], acc[c4*4+3]);
}

// ---------------- launch ----------------

extern "C" void kernel_launch(void* const* d_in, const int* in_sizes, int n_in,
                              void* d_out, int out_size, void* d_ws, size_t ws_size,
                              hipStream_t stream) {
  const float* x   = (const float*)d_in[0];
  const int*   ei  = (const int*)d_in[1];
  const float* W1l = (const float*)d_in[2];
  const float* b1  = (const float*)d_in[3];
  const float* W1r = (const float*)d_in[4];
  const float* W2l = (const float*)d_in[5];
  const float* b2  = (const float*)d_in[6];
  const float* W2r = (const float*)d_in[7];
  const float* W3l = (const float*)d_in[8];
  const float* b3  = (const float*)d_in[9];
  const float* W3r = (const float*)d_in[10];

  const int N = in_sizes[0] / D;       // 100000
  const int E = in_sizes[1] / 2;       // 1600000
  const int* src = ei;
  const int* dst = ei + E;

  char* ws = (char*)d_ws;
  auto alloc = [&](size_t bytes) -> void* {
    void* p = (void*)ws;
    ws += (bytes + 255) & ~(size_t)255;
    return p;
  };
  int*   deg_i    = (int*)  alloc((size_t)N * 4);
  int*   csr_off  = (int*)  alloc((size_t)(N + 1) * 4);
  int*   fill_pos = (int*)  alloc((size_t)N * 4);
  int*   bsum     = (int*)  alloc(1024);
  int*   bsum_s   = (int*)  alloc(1024);
  float* deg_inv  = (float*)alloc((size_t)N * 4);
  int*   csr_src  = (int*)  alloc((size_t)E * 4);
  float* agg      = (float*)alloc((size_t)N * D * 4);
  float* hbuf     = (float*)alloc((size_t)N * D * 4);

  hipMemsetAsync(deg_i, 0, (size_t)N * 4, stream);
  hipMemsetAsync(fill_pos, 0, (size_t)N * 4, stream);

  // CSR build
  count_deg_k<<<(E + 255) / 256, 256, 0, stream>>>(dst, deg_i, E);
  const int NB = (N + 1023) / 1024;
  scan_excl_k<<<NB, 1024, 0, stream>>>(deg_i, csr_off, bsum, N);
  scan_excl_k<<<1, 128, 0, stream>>>(bsum, bsum_s, nullptr, NB);
  finalize_k<<<(N + 255) / 256, 256, 0, stream>>>(csr_off, bsum_s, deg_i, deg_inv, N, E);
  fill_csr_k<<<(E + 255) / 256, 256, 0, stream>>>(src, dst, csr_off, fill_pos, csr_src, E);

  const int gblocks = (N + 127) / 128;
  const int ablocks = (N + 7) / 8;
  // layer 1
  aggregate_k<<<ablocks, 256, 0, stream>>>(x, csr_off, csr_src, deg_inv, agg, N);
  gemm2_relu_k<<<gblocks, 256, 0, stream>>>(agg, x, W1l, W1r, b1, hbuf, N);
  // layer 2 (in-place h: each block reads only its own row tile before writing it)
  aggregate_k<<<ablocks, 256, 0, stream>>>(hbuf, csr_off, csr_src, deg_inv, agg, N);
  gemm2_relu_k<<<gblocks, 256, 0, stream>>>(agg, hbuf, W2l, W2r, b2, hbuf, N);
  // layer 3 + log_softmax
  aggregate_k<<<ablocks, 256, 0, stream>>>(hbuf, csr_off, csr_src, deg_inv, agg, N);
  layer3_k<<<(N + 127) / 128, 128, 0, stream>>>(agg, hbuf, W3l, b3, W3r, (float*)d_out, N);
}

// Round 3
// 691.126 us; speedup vs baseline: 1.8874x; 1.2546x over previous
//
#include <hip/hip_runtime.h>
#include <math.h>

#define D 128
#define NCLS 40

typedef unsigned int u32;

__device__ inline float bflo(u32 u){ return __uint_as_float(u << 16); }
__device__ inline float bfhi(u32 u){ return __uint_as_float(u & 0xffff0000u); }
// pack two fp32 -> bf16x2 (round-to-nearest-even)
__device__ inline u32 pack2bf(float a, float b){
  u32 ua = __float_as_uint(a), ub = __float_as_uint(b);
  ua += 0x7fffu + ((ua >> 16) & 1u);
  ub += 0x7fffu + ((ub >> 16) & 1u);
  return (ua >> 16) | (ub & 0xffff0000u);
}

// ---------------- fp32 -> bf16 conversion ----------------
__global__ __launch_bounds__(256) void f2bf_k(const float4* __restrict__ in,
                                              uint2* __restrict__ out, int n4){
  int i = blockIdx.x * 256 + threadIdx.x;
  if (i < n4){
    float4 v = in[i];
    out[i] = make_uint2(pack2bf(v.x, v.y), pack2bf(v.z, v.w));
  }
}

// ---------------- CSR build ----------------

__global__ void count_deg_k(const int* __restrict__ dst, int* __restrict__ deg, int E){
  int e = blockIdx.x * blockDim.x + threadIdx.x;
  if (e < E) atomicAdd(&deg[dst[e]], 1);
}

__global__ void scan_excl_k(const int* __restrict__ in, int* __restrict__ out,
                            int* __restrict__ bsum, int n){
  __shared__ int sm[1024];
  int tid = threadIdx.x;
  int i = blockIdx.x * blockDim.x + tid;
  int v = (i < n) ? in[i] : 0;
  sm[tid] = v; __syncthreads();
  int acc = v;
  for (int off = 1; off < (int)blockDim.x; off <<= 1){
    int t = (tid >= off) ? sm[tid - off] : 0;
    __syncthreads();
    acc += t; sm[tid] = acc;
    __syncthreads();
  }
  if (i < n) out[i] = acc - v;          // exclusive
  if (bsum && tid == (int)blockDim.x - 1) bsum[blockIdx.x] = acc;
}

__global__ void finalize_k(int* __restrict__ csr_off, const int* __restrict__ bsum_s,
                           const int* __restrict__ deg, float* __restrict__ deg_inv,
                           int n, int E){
  int i = blockIdx.x * blockDim.x + threadIdx.x;
  if (i < n){
    csr_off[i] += bsum_s[i >> 10];
    deg_inv[i] = 1.0f / fmaxf((float)deg[i], 1.0f);
  }
  if (i == 0) csr_off[n] = E;
}

__global__ void fill_csr_k(const int* __restrict__ src, const int* __restrict__ dst,
                           const int* __restrict__ coff, int* __restrict__ pos,
                           int* __restrict__ csr_src, int E){
  int e = blockIdx.x * blockDim.x + threadIdx.x;
  if (e < E){
    int d = dst[e];
    int p = atomicAdd(&pos[d], 1);
    csr_src[coff[d] + p] = src[e];
  }
}

// ---------------- mean aggregation (bf16 gather via CSR) ----------------
// 16 lanes per node (uint4 = 8 bf16 each => full 256B row); 16 nodes per 256-thread block
__device__ inline void add8(float* acc, uint4 v){
  acc[0] += bflo(v.x); acc[1] += bfhi(v.x);
  acc[2] += bflo(v.y); acc[3] += bfhi(v.y);
  acc[4] += bflo(v.z); acc[5] += bfhi(v.z);
  acc[6] += bflo(v.w); acc[7] += bfhi(v.w);
}

__global__ __launch_bounds__(256) void aggregate_k(
    const u32* __restrict__ feat, const int* __restrict__ coff,
    const int* __restrict__ csr_src, const float* __restrict__ deg_inv,
    u32* __restrict__ agg, int n)
{
  const int g = threadIdx.x >> 4;
  const int lane = threadIdx.x & 15;
  const int node = blockIdx.x * 16 + g;
  if (node >= n) return;
  const int lo = coff[node], hi = coff[node + 1];
  const uint4* __restrict__ f4 = (const uint4*)feat;   // 16 uint4 per row
  float acc[8] = {0.f,0.f,0.f,0.f,0.f,0.f,0.f,0.f};
  int e = lo;
  for (; e + 1 < hi; e += 2){
    int s0 = csr_src[e], s1 = csr_src[e + 1];
    uint4 v0 = f4[(size_t)s0 * 16 + lane];
    uint4 v1 = f4[(size_t)s1 * 16 + lane];
    add8(acc, v0); add8(acc, v1);
  }
  if (e < hi){
    uint4 v0 = f4[(size_t)csr_src[e] * 16 + lane];
    add8(acc, v0);
  }
  const float di = deg_inv[node];
  uint4 o;
  o.x = pack2bf(acc[0] * di, acc[1] * di);
  o.y = pack2bf(acc[2] * di, acc[3] * di);
  o.z = pack2bf(acc[4] * di, acc[5] * di);
  o.w = pack2bf(acc[6] * di, acc[7] * di);
  ((uint4*)agg)[(size_t)node * 16 + lane] = o;
}

// ---------------- dense: out = relu(A1@B1 + bias + A2@B2) ----------------
// A1,A2: bf16 [n,128]; B1,B2: fp32 [128,128]; out: bf16 [n,128]
__global__ __launch_bounds__(256) void gemm2_relu_k(
    const u32* __restrict__ A1, const u32* __restrict__ A2,
    const float* __restrict__ B1, const float* __restrict__ B2,
    const float* __restrict__ bias, u32* __restrict__ out, int n)
{
  __shared__ float As[8][128];
  __shared__ float Bs[8][128];
  const int tid = threadIdx.x;
  const int row0 = blockIdx.x * 128;
  const int tx = tid & 15, ty = tid >> 4;
  const int lam = tid >> 1, lak = (tid & 1) * 4;
  const int lbk = tid >> 5, lbn = (tid & 31) * 4;
  float acc[8][8];
  #pragma unroll
  for (int i = 0; i < 8; i++)
    #pragma unroll
    for (int j = 0; j < 8; j++) acc[i][j] = 0.f;

  const int arow = row0 + lam;
  for (int kt = 0; kt < 32; ++kt){
    const int kg = kt * 8;
    const u32* Ap = (kg < 128) ? A1 : A2;
    const float* Bp = (kg < 128) ? B1 : B2;
    const int kl = kg & 127;
    uint2 av = make_uint2(0, 0);
    if (arow < n) av = *(const uint2*)(Ap + (size_t)arow * 64 + ((kl + lak) >> 1));
    float4 bv = *(const float4*)(Bp + (size_t)(kl + lbk) * 128 + lbn);
    As[lak + 0][lam] = bflo(av.x); As[lak + 1][lam] = bfhi(av.x);
    As[lak + 2][lam] = bflo(av.y); As[lak + 3][lam] = bfhi(av.y);
    *(float4*)&Bs[lbk][lbn] = bv;
    __syncthreads();
    #pragma unroll
    for (int kk = 0; kk < 8; kk++){
      float a[8], b[8];
      *(float4*)&a[0] = *(const float4*)&As[kk][ty * 8];
      *(float4*)&a[4] = *(const float4*)&As[kk][ty * 8 + 4];
      *(float4*)&b[0] = *(const float4*)&Bs[kk][tx * 8];
      *(float4*)&b[4] = *(const float4*)&Bs[kk][tx * 8 + 4];
      #pragma unroll
      for (int i = 0; i < 8; i++)
        #pragma unroll
        for (int j = 0; j < 8; j++) acc[i][j] = fmaf(a[i], b[j], acc[i][j]);
    }
    __syncthreads();
  }
  float bcol[8];
  #pragma unroll
  for (int j = 0; j < 8; j++) bcol[j] = bias[tx * 8 + j];
  #pragma unroll
  for (int i = 0; i < 8; i++){
    int r = row0 + ty * 8 + i;
    if (r < n){
      float v[8];
      #pragma unroll
      for (int j = 0; j < 8; j++) v[j] = fmaxf(acc[i][j] + bcol[j], 0.f);
      uint4 o;
      o.x = pack2bf(v[0], v[1]); o.y = pack2bf(v[2], v[3]);
      o.z = pack2bf(v[4], v[5]); o.w = pack2bf(v[6], v[7]);
      *(uint4*)(out + (size_t)r * 64 + tx * 4) = o;
    }
  }
}

// ---------------- layer 3 + log_softmax: one THREAD per node; W3 in LDS ----------------
__global__ __launch_bounds__(128) void layer3_k(
    const u32* __restrict__ agg, const u32* __restrict__ h,
    const float* __restrict__ Wl, const float* __restrict__ bias,
    const float* __restrict__ Wr, float* __restrict__ out, int n)
{
  __shared__ float Wls[D * NCLS];   // 20 KB
  __shared__ float Wrs[D * NCLS];   // 20 KB
  const int tid = threadIdx.x;
  for (int i = tid * 4; i < D * NCLS; i += 128 * 4){
    *(float4*)&Wls[i] = *(const float4*)&Wl[i];
    *(float4*)&Wrs[i] = *(const float4*)&Wr[i];
  }
  __syncthreads();
  const int node = blockIdx.x * 128 + tid;
  if (node >= n) return;
  const uint4* __restrict__ ar = (const uint4*)(agg + (size_t)node * 64);
  const uint4* __restrict__ hr = (const uint4*)(h + (size_t)node * 64);
  float acc[NCLS];
  #pragma unroll
  for (int c = 0; c < NCLS; c++) acc[c] = bias[c];
  for (int kc = 0; kc < 16; kc++){      // 16 uint4 chunks x 8 elems
    uint4 a = ar[kc];
    uint4 b = hr[kc];
    float av[8], hv[8];
    av[0]=bflo(a.x); av[1]=bfhi(a.x); av[2]=bflo(a.y); av[3]=bfhi(a.y);
    av[4]=bflo(a.z); av[5]=bfhi(a.z); av[6]=bflo(a.w); av[7]=bfhi(a.w);
    hv[0]=bflo(b.x); hv[1]=bfhi(b.x); hv[2]=bflo(b.y); hv[3]=bfhi(b.y);
    hv[4]=bflo(b.z); hv[5]=bfhi(b.z); hv[6]=bflo(b.w); hv[7]=bfhi(b.w);
    #pragma unroll
    for (int j = 0; j < 8; j++){
      const float* __restrict__ wl = &Wls[(kc * 8 + j) * NCLS];
      const float* __restrict__ wr = &Wrs[(kc * 8 + j) * NCLS];
      #pragma unroll
      for (int c = 0; c < NCLS; c++)
        acc[c] = fmaf(av[j], wl[c], fmaf(hv[j], wr[c], acc[c]));
    }
  }
  float m = -INFINITY;
  #pragma unroll
  for (int c = 0; c < NCLS; c++) m = fmaxf(m, acc[c]);
  float s = 0.f;
  #pragma unroll
  for (int c = 0; c < NCLS; c++) s += __expf(acc[c] - m);
  const float ls = m + logf(s);
  float* op = out + (size_t)node * NCLS;
  #pragma unroll
  for (int c = 0; c < NCLS; c++) acc[c] -= ls;
  #pragma unroll
  for (int c4 = 0; c4 < NCLS / 4; c4++)
    *(float4*)(op + c4 * 4) = make_float4(acc[c4*4], acc[c4*4+1], acc[c4*4+2], acc[c4*4+3]);
}

// ---------------- launch ----------------

extern "C" void kernel_launch(void* const* d_in, const int* in_sizes, int n_in,
                              void* d_out, int out_size, void* d_ws, size_t ws_size,
                              hipStream_t stream) {
  const float* x   = (const float*)d_in[0];
  const int*   ei  = (const int*)d_in[1];
  const float* W1l = (const float*)d_in[2];
  const float* b1  = (const float*)d_in[3];
  const float* W1r = (const float*)d_in[4];
  const float* W2l = (const float*)d_in[5];
  const float* b2  = (const float*)d_in[6];
  const float* W2r = (const float*)d_in[7];
  const float* W3l = (const float*)d_in[8];
  const float* b3  = (const float*)d_in[9];
  const float* W3r = (const float*)d_in[10];

  const int N = in_sizes[0] / D;       // 100000
  const int E = in_sizes[1] / 2;       // 1600000
  const int* src = ei;
  const int* dst = ei + E;

  char* ws = (char*)d_ws;
  auto alloc = [&](size_t bytes) -> void* {
    void* p = (void*)ws;
    ws += (bytes + 255) & ~(size_t)255;
    return p;
  };
  int*   deg_i    = (int*)  alloc((size_t)N * 4);
  int*   csr_off  = (int*)  alloc((size_t)(N + 1) * 4);
  int*   fill_pos = (int*)  alloc((size_t)N * 4);
  int*   bsum     = (int*)  alloc(1024);
  int*   bsum_s   = (int*)  alloc(1024);
  float* deg_inv  = (float*)alloc((size_t)N * 4);
  int*   csr_src  = (int*)  alloc((size_t)E * 4);
  u32*   xb       = (u32*)  alloc((size_t)N * D * 2);   // x in bf16
  u32*   agg      = (u32*)  alloc((size_t)N * D * 2);   // bf16
  u32*   hbuf     = (u32*)  alloc((size_t)N * D * 2);   // bf16

  hipMemsetAsync(deg_i, 0, (size_t)N * 4, stream);
  hipMemsetAsync(fill_pos, 0, (size_t)N * 4, stream);

  // x -> bf16
  const int n4 = N * D / 4;
  f2bf_k<<<(n4 + 255) / 256, 256, 0, stream>>>((const float4*)x, (uint2*)xb, n4);

  // CSR build
  count_deg_k<<<(E + 255) / 256, 256, 0, stream>>>(dst, deg_i, E);
  const int NB = (N + 1023) / 1024;
  scan_excl_k<<<NB, 1024, 0, stream>>>(deg_i, csr_off, bsum, N);
  scan_excl_k<<<1, 128, 0, stream>>>(bsum, bsum_s, nullptr, NB);
  finalize_k<<<(N + 255) / 256, 256, 0, stream>>>(csr_off, bsum_s, deg_i, deg_inv, N, E);
  fill_csr_k<<<(E + 255) / 256, 256, 0, stream>>>(src, dst, csr_off, fill_pos, csr_src, E);

  const int gblocks = (N + 127) / 128;
  const int ablocks = (N + 15) / 16;
  // layer 1
  aggregate_k<<<ablocks, 256, 0, stream>>>(xb, csr_off, csr_src, deg_inv, agg, N);
  gemm2_relu_k<<<gblocks, 256, 0, stream>>>(agg, xb, W1l, W1r, b1, hbuf, N);
  // layer 2 (in-place h: each block reads only its own row tile before writing it)
  aggregate_k<<<ablocks, 256, 0, stream>>>(hbuf, csr_off, csr_src, deg_inv, agg, N);
  gemm2_relu_k<<<gblocks, 256, 0, stream>>>(agg, hbuf, W2l, W2r, b2, hbuf, N);
  // layer 3 + log_softmax
  aggregate_k<<<ablocks, 256, 0, stream>>>(hbuf, csr_off, csr_src, deg_inv, agg, N);
  layer3_k<<<(N + 127) / 128, 128, 0, stream>>>(agg, hbuf, W3l, b3, W3r, (float*)d_out, N);
}